// Round 8
// baseline (162.545 us; speedup 1.0000x reference)
//
#include <hip/hip_runtime.h>

#define T_LEN   65536
#define P       64
#define BASE    4096           // base length produced by the in-block ladder
#define K1_THREADS 256
#define W_TILE  1024
#define BCHUNK  8
#define VOFF    65536          // V_k published at R[VOFF + 80*k .. +64], k=1..15

typedef float f4 __attribute__((ext_vector_type(4)));

// ---------------------------------------------------------------------------
// means[t] = bias * R[t], R = step response of the AR(64) filter:
//   R[t] = sum_k params[k]*R[t-1-k] + 1,  R[t<0] = 0
// Extension identity:  R[t + D] = R[t] + sum_i V_D[i] * R[t-i]   (t >= 64)
// R13: tree rewritten. Evidence (R10: per-block chain ~35us at FULL clock;
// R12: stage count is nearly free) says ar_k1 is bound by dependent-chain
// latency, dominated by the tree's per-lane scalar convs (65 serialized
// LDS-read->fma per output). Fix:
//  (a) generalized ADD — any node tail can be advanced by any computed V,
//      giving a DEPTH-4 schedule from tail_1 = R[3584..4096):
//      L0: 2=D(1) | L1: 4=D(2), 3=A(2,V1) | L2: 8=D(4), 5..7=A(4,V1..V3)
//      L3: 9..15=A(8,V1..V7).  4 barriers (was 12).
//  (b) every tree conv uses the ladder's f4-blocked form (ds_read_b128
//      window in registers, i-ascending fma order — bit-identical per
//      element vs the scalar loop): ~600cy/step instead of ~3-5Kcy.
// Ladder / serial stage / epilogue kernel are R12-verbatim.
// ---------------------------------------------------------------------------

// Fused tap+reduce (R10-validated bit-exact): lane j builds the four 16-wide
// partials of W0[j] in R7's order, sums left-assoc, then V[j]=W0[j]-W0[j-1]
// via shfl_up. Lane 63 writes V[64] = -W0[63]. Reads only td[wd-64..wd).
__device__ __forceinline__ void tapV_wave(const float* __restrict__ td, int wd,
                                          const float* __restrict__ p,
                                          float* __restrict__ Vdst, int lane) {
    const int j = lane;
    float w0 = 0.f, w1 = 0.f, w2 = 0.f, w3 = 0.f;
    #pragma unroll
    for (int mm = 0; mm < 16; ++mm) w0 = fmaf(p[mm + j],      td[wd - 1  - mm], w0);
    #pragma unroll
    for (int mm = 0; mm < 16; ++mm) w1 = fmaf(p[16 + mm + j], td[wd - 17 - mm], w1);
    #pragma unroll
    for (int mm = 0; mm < 16; ++mm) w2 = fmaf(p[32 + mm + j], td[wd - 33 - mm], w2);
    #pragma unroll
    for (int mm = 0; mm < 16; ++mm) w3 = fmaf(p[48 + mm + j], td[wd - 49 - mm], w3);
    const float wj  = ((w0 + w1) + w2) + w3;
    const float wm1 = __shfl_up(wj, 1);
    Vdst[j] = (j == 0) ? wj : (wj - wm1);
    if (j == 63) Vdst[64] = 0.0f - wj;
}

// f4-blocked tree conv (ladder's proven pattern): out[x] = s0[x] +
// sum_{i=0..64} V[i]*s0[x-i], with s0 = tail+64, w_out = w_tail-64.
// Per-element fma order = scalar i-ascending loop (bit-identical).
// tail must be 16B-aligned; one wave (64 lanes) executes it.
__device__ __forceinline__ void treeconv(const float* __restrict__ tail,
                                         int w_out,
                                         const float* __restrict__ V,
                                         float* __restrict__ outb, int lane) {
    const f4* __restrict__ t4 = reinterpret_cast<const f4*>(tail);
    const f4* __restrict__ V4 = reinterpret_cast<const f4*>(V);
    f4* __restrict__ o4 = reinterpret_cast<f4*>(outb);
    const int nq = w_out >> 2;
    #pragma unroll 1
    for (int q = lane; q < nq; q += 64) {
        f4 w4[17];
        #pragma unroll
        for (int j = 0; j < 17; ++j) w4[j] = t4[q + j];
        float a0 = w4[16].x, a1 = w4[16].y, a2 = w4[16].z, a3 = w4[16].w;
        #pragma unroll
        for (int g = 0; g < 16; ++g) {   // i = 4g..4g+3
            const f4 v  = V4[g];
            const f4 hi = w4[16 - g];
            const f4 lo = w4[15 - g];
            a0 = fmaf(v.x, hi.x, a0); a1 = fmaf(v.x, hi.y, a1);
            a2 = fmaf(v.x, hi.z, a2); a3 = fmaf(v.x, hi.w, a3);
            a0 = fmaf(v.y, lo.w, a0); a1 = fmaf(v.y, hi.x, a1);
            a2 = fmaf(v.y, hi.y, a2); a3 = fmaf(v.y, hi.z, a3);
            a0 = fmaf(v.z, lo.z, a0); a1 = fmaf(v.z, lo.w, a1);
            a2 = fmaf(v.z, hi.x, a2); a3 = fmaf(v.z, hi.y, a3);
            a0 = fmaf(v.w, lo.y, a0); a1 = fmaf(v.w, lo.z, a1);
            a2 = fmaf(v.w, lo.w, a2); a3 = fmaf(v.w, hi.x, a3);
        }
        const float v64 = V[64];
        a0 = fmaf(v64, w4[0].x, a0); a1 = fmaf(v64, w4[0].y, a1);
        a2 = fmaf(v64, w4[0].z, a2); a3 = fmaf(v64, w4[0].w, a3);
        f4 o; o.x = a0; o.y = a1; o.z = a2; o.w = a3;
        o4[q] = o;
    }
}

__global__ __launch_bounds__(K1_THREADS, 1) void ar_k1(const float* __restrict__ params,
                                                       float* __restrict__ R) {
    __shared__ __align__(16) float Rl[BASE];
    __shared__ float p[128];          // zero-padded: p[64..127] = 0 masks m+j>63
    __shared__ __align__(16) float Vs[68];
    __shared__ __align__(16) float Vnode[16][68];   // V_k, k=1..15
    __shared__ __align__(16) float T2[448];         // tail of node 2
    __shared__ __align__(16) float T4[384];         // tail of node 4
    __shared__ __align__(16) float T8[320];         // tail of node 8
    __shared__ __align__(16) float Tw[4][384];      // per-wave transient tails
    const int tid = threadIdx.x;
    if (tid < 128) p[tid] = (tid < P) ? params[tid] : 0.f;
    __syncthreads();

    // ---- serial stage: lane t holds transposed-form state (verbatim) ----
    if (tid < 64) {
        float z = 0.f;
        const float pk = p[tid];
        #pragma unroll 1
        for (int t = 0; t < 64; ++t) {
            float y  = __shfl(z, 0) + 1.0f;   // R[t]
            float zn = __shfl_down(z, 1);
            if (tid == 63) zn = 0.f;
            z = fmaf(pk, y, zn);
            if (tid == 0) Rl[t] = y;
        }
    }
    __syncthreads();

    // ---- ladder 64 -> 4096 in LDS (R12-verbatim) ----
    #pragma unroll 1
    for (int L = 64; L <= BASE / 2; L <<= 1) {
        if (tid < 64) tapV_wave(Rl, L, p, Vs, tid);
        __syncthreads();
        if (tid < P) {                          // boundary tau in [0,64)
            const int tau = tid;
            float acc = Rl[tau];
            #pragma unroll
            for (int i = 0; i < P; ++i) {
                const int idx = (tau - i) > 0 ? (tau - i) : 0;
                const float v = (i <= tau) ? Vs[i] : 0.f;
                acc = fmaf(v, Rl[idx], acc);
            }
            Rl[L + tau] = acc;
        }
        {                                       // blocked tau in [64,L)
            const f4* __restrict__ Rl4 = reinterpret_cast<const f4*>(Rl);
            f4* __restrict__ Rl4w = reinterpret_cast<f4*>(Rl);
            const f4* __restrict__ V4 = reinterpret_cast<const f4*>(Vs);
            const int nq = (L - 64) >> 2;
            #pragma unroll 1
            for (int q = tid; q < nq; q += K1_THREADS) {
                f4 w4[17];
                #pragma unroll
                for (int j = 0; j < 17; ++j) w4[j] = Rl4[q + j];
                float a0 = w4[16].x, a1 = w4[16].y, a2 = w4[16].z, a3 = w4[16].w;
                #pragma unroll
                for (int g = 0; g < 16; ++g) {   // i = 4g..4g+3
                    const f4 v  = V4[g];
                    const f4 hi = w4[16 - g];
                    const f4 lo = w4[15 - g];
                    a0 = fmaf(v.x, hi.x, a0); a1 = fmaf(v.x, hi.y, a1);
                    a2 = fmaf(v.x, hi.z, a2); a3 = fmaf(v.x, hi.w, a3);
                    a0 = fmaf(v.y, lo.w, a0); a1 = fmaf(v.y, hi.x, a1);
                    a2 = fmaf(v.y, hi.y, a2); a3 = fmaf(v.y, hi.z, a3);
                    a0 = fmaf(v.z, lo.z, a0); a1 = fmaf(v.z, lo.w, a1);
                    a2 = fmaf(v.z, hi.x, a2); a3 = fmaf(v.z, hi.y, a3);
                    a0 = fmaf(v.w, lo.y, a0); a1 = fmaf(v.w, lo.z, a1);
                    a2 = fmaf(v.w, lo.w, a2); a3 = fmaf(v.w, hi.x, a3);
                }
                const float v64 = Vs[64];
                a0 = fmaf(v64, w4[0].x, a0); a1 = fmaf(v64, w4[0].y, a1);
                a2 = fmaf(v64, w4[0].z, a2); a3 = fmaf(v64, w4[0].w, a3);
                f4 o; o.x = a0; o.y = a1; o.z = a2; o.w = a3;
                Rl4w[((L + 64) >> 2) + q] = o;
            }
        }
        __syncthreads();
    }

    // ---- publish base R[0..4096) (global writes hide under the tree) ----
    #pragma unroll 1
    for (int j4 = tid; j4 < BASE / 4; j4 += K1_THREADS)
        reinterpret_cast<f4*>(R)[j4] = reinterpret_cast<const f4*>(Rl)[j4];

    // ---- depth-4 tree (wave-parallel, f4-blocked convs) ----
    const int w = tid >> 6, lane = tid & 63;
    // L0 (wave 0): V_1 tap (bit-identical to R12), node 2 = D(1)
    if (w == 0) {
        tapV_wave(Rl + 3840, 256, p, Vnode[1], lane);   // V_1
        treeconv(Rl + 3584, 448, Vnode[1], T2, lane);   // tail_2
        tapV_wave(T2, 448, p, Vnode[2], lane);          // V_2
    }
    __syncthreads();
    // L1: 4 = D(2) on wave0, 3 = A(2,V1) on wave1
    if (w == 0) {
        treeconv(T2, 384, Vnode[2], T4, lane);
        tapV_wave(T4, 384, p, Vnode[4], lane);
    } else if (w == 1) {
        treeconv(T2, 384, Vnode[1], Tw[1], lane);
        tapV_wave(Tw[1], 384, p, Vnode[3], lane);
    }
    __syncthreads();
    // L2: 8 = D(4) on wave0; 5,6,7 = A(4, V1..V3) on waves 1..3
    if (w == 0) {
        treeconv(T4, 320, Vnode[4], T8, lane);
        tapV_wave(T8, 320, p, Vnode[8], lane);
    } else {
        treeconv(T4, 320, Vnode[w], Tw[w], lane);
        tapV_wave(Tw[w], 320, p, Vnode[4 + w], lane);
    }
    __syncthreads();
    // L3: 9..12 = A(8, V1..V4) ; 13..15 = A(8, V5..V7)
    {
        treeconv(T8, 256, Vnode[1 + w], Tw[w], lane);
        tapV_wave(Tw[w], 256, p, Vnode[9 + w], lane);
        if (w < 3) {
            treeconv(T8, 256, Vnode[5 + w], Tw[w], lane);
            tapV_wave(Tw[w], 256, p, Vnode[13 + w], lane);
        }
    }
    __syncthreads();

    // ---- publish V_1..V_15 ----
    #pragma unroll 1
    for (int j = tid; j < 15 * 80; j += K1_THREADS) {
        const int k = j / 80 + 1, i = j - (k - 1) * 80;
        if (i < 65) R[VOFF + k * 80 + i] = Vnode[k][i];
    }
}

// ---------------------------------------------------------------------------
// Fused extension + output (R7/R12-verbatim): tile [t0, t0+1024) with
// k = t0>>12, tau0 = t0&4095: R[t] = win[64+x] + sum_i V_k[i]*win[64+x-i].
// Grid = 64 t-tiles x 32 batch-chunks = 2048 blocks.
// ---------------------------------------------------------------------------
__global__ __launch_bounds__(256) void ar_out_fused(const float* __restrict__ R,
                                                    const float* __restrict__ bias,
                                                    const float* __restrict__ noise,
                                                    float* __restrict__ out) {
    __shared__ __align__(16) float win[1088];   // R[tau0-64 .. tau0+1024)
    __shared__ __align__(16) float Vl[68];
    const int tid  = threadIdx.x;
    const int tile = blockIdx.x & 63;
    const int bc   = blockIdx.x >> 6;
    const int t0   = tile * W_TILE;
    const float b  = bias[0];
    const int k    = t0 >> 12;                  // 0..15
    const f4* __restrict__ Rg4 = reinterpret_cast<const f4*>(R);

    f4 rt;
    if (k == 0) {
        const f4 r = Rg4[(t0 >> 2) + tid];      // bitwise-identical base path
        rt.x = b * r.x; rt.y = b * r.y; rt.z = b * r.z; rt.w = b * r.w;
    } else {
        const int tau0 = t0 & 4095;
        if (tid < 65) Vl[tid] = R[VOFF + k * 80 + tid];
        f4* __restrict__ win4 = reinterpret_cast<f4*>(win);
        for (int j4 = tid; j4 < 272; j4 += 256) {
            const int u = tau0 - 64 + 4 * j4;   // multiple of 4
            f4 v;
            if (u >= 0) v = Rg4[u >> 2];
            else { v.x = 0.f; v.y = 0.f; v.z = 0.f; v.w = 0.f; }
            win4[j4] = v;
        }
        __syncthreads();
        // 65-tap conv, f4-blocked (same index algebra as the ladder's loop)
        const f4* __restrict__ V4 = reinterpret_cast<const f4*>(Vl);
        f4 w4[17];
        #pragma unroll
        for (int j = 0; j < 17; ++j) w4[j] = win4[tid + j];
        float a0 = w4[16].x, a1 = w4[16].y, a2 = w4[16].z, a3 = w4[16].w;
        #pragma unroll
        for (int g = 0; g < 16; ++g) {
            const f4 v  = V4[g];
            const f4 hi = w4[16 - g];
            const f4 lo = w4[15 - g];
            a0 = fmaf(v.x, hi.x, a0); a1 = fmaf(v.x, hi.y, a1);
            a2 = fmaf(v.x, hi.z, a2); a3 = fmaf(v.x, hi.w, a3);
            a0 = fmaf(v.y, lo.w, a0); a1 = fmaf(v.y, hi.x, a1);
            a2 = fmaf(v.y, hi.y, a2); a3 = fmaf(v.y, hi.z, a3);
            a0 = fmaf(v.z, lo.z, a0); a1 = fmaf(v.z, lo.w, a1);
            a2 = fmaf(v.z, hi.x, a2); a3 = fmaf(v.z, hi.y, a3);
            a0 = fmaf(v.w, lo.y, a0); a1 = fmaf(v.w, lo.z, a1);
            a2 = fmaf(v.w, lo.w, a2); a3 = fmaf(v.w, hi.x, a3);
        }
        const float v64 = Vl[64];
        a0 = fmaf(v64, w4[0].x, a0); a1 = fmaf(v64, w4[0].y, a1);
        a2 = fmaf(v64, w4[0].z, a2); a3 = fmaf(v64, w4[0].w, a3);
        rt.x = b * a0; rt.y = b * a1; rt.z = b * a2; rt.w = b * a3;
    }

    // stream 8 batch rows: 1 f4 column per thread, R tile in registers
    const int nb4 = T_LEN >> 2;
    const int col = (t0 >> 2) + tid;
    const f4* __restrict__ n4 = reinterpret_cast<const f4*>(noise);
    f4* __restrict__ o4 = reinterpret_cast<f4*>(out);
    #pragma unroll
    for (int bi = 0; bi < BCHUNK; ++bi) {
        const int idx = (bc * BCHUNK + bi) * nb4 + col;
        const f4 n = __builtin_nontemporal_load(n4 + idx);
        f4 o;
        o.x = fmaf(0.3f, n.x, rt.x);
        o.y = fmaf(0.3f, n.y, rt.y);
        o.z = fmaf(0.3f, n.z, rt.z);
        o.w = fmaf(0.3f, n.w, rt.w);
        __builtin_nontemporal_store(o, o4 + idx);
    }
}

extern "C" void kernel_launch(void* const* d_in, const int* in_sizes, int n_in,
                              void* d_out, int out_size, void* d_ws, size_t ws_size,
                              hipStream_t stream) {
    const float* params = (const float*)d_in[0];
    const float* bias   = (const float*)d_in[1];
    const float* noise  = (const float*)d_in[2];
    float* out = (float*)d_out;
    float* R   = (float*)d_ws;   // base R[0..4096) + V_1..15 at VOFF

    hipLaunchKernelGGL(ar_k1, dim3(1), dim3(K1_THREADS), 0, stream, params, R);
    hipLaunchKernelGGL(ar_out_fused, dim3(64 * 32), dim3(256), 0, stream,
                       R, bias, noise, out);
}